// Round 7
// baseline (10522.726 us; speedup 1.0000x reference)
//
#include <hip/hip_runtime.h>

#define BB   512
#define SS   256
#define NIN  128
#define DH   1024
#define DC   1152   // NIN + DH
#define NOUT 128
#define EPSV 1e-5f

typedef _Float16 f16;
typedef _Float16 f16x8 __attribute__((ext_vector_type(8)));
typedef _Float16 f16x4 __attribute__((ext_vector_type(4)));
typedef float    f32x4 __attribute__((ext_vector_type(4)));

__device__ __forceinline__ float sigmoid_(float x) { return 1.0f / (1.0f + __expf(-x)); }
__device__ __forceinline__ float tanh_(float x) {
    x = fminf(fmaxf(x, -15.0f), 15.0f);
    float e = __expf(2.0f * x);
    return (e - 1.0f) / (e + 1.0f);
}

// ---------------- weight conversion (fp32 -> fp16), once per launch ----------------
__global__ void k_convert(const float* __restrict__ Wu, const float* __restrict__ Wr,
                          const float* __restrict__ Wh_, const float* __restrict__ Wo_,
                          f16* __restrict__ wur, f16* __restrict__ wh, f16* __restrict__ wo)
{
    const int stride = gridDim.x * blockDim.x;
    const int i0 = blockIdx.x * blockDim.x + threadIdx.x;
    for (int i = i0; i < 2048 * 1152 / 4; i += stride) {
        int base = i * 4;
        int n = base / 1152, k = base % 1152;
        const float* src = (n < 1024) ? (Wu + (size_t)n * 1152 + k) : (Wr + (size_t)(n - 1024) * 1152 + k);
        float4 v = *(const float4*)src;
        f16x4 o; o[0] = (f16)v.x; o[1] = (f16)v.y; o[2] = (f16)v.z; o[3] = (f16)v.w;
        *(f16x4*)(wur + base) = o;
    }
    for (int i = i0; i < 1024 * 1152 / 4; i += stride) {
        int base = i * 4;
        float4 v = *(const float4*)(Wh_ + base);
        f16x4 o; o[0] = (f16)v.x; o[1] = (f16)v.y; o[2] = (f16)v.z; o[3] = (f16)v.w;
        *(f16x4*)(wh + base) = o;
    }
    for (int i = i0; i < 128 * 1024 / 4; i += stride) {
        int base = i * 4;
        float4 v = *(const float4*)(Wo_ + base);
        f16x4 o; o[0] = (f16)v.x; o[1] = (f16)v.y; o[2] = (f16)v.z; o[3] = (f16)v.w;
        *(f16x4*)(wo + base) = o;
    }
}

// ---------------- init: comb = [x_0, 0], h32 = 0, stats = 0 ----------------
__global__ void k_init(const float* __restrict__ X, f16* __restrict__ comb, float* __restrict__ h32,
                       float* __restrict__ ssum_ur, float* __restrict__ ssq_ur,
                       float* __restrict__ ssum_c, float* __restrict__ ssq_c)
{
    const int stride = gridDim.x * blockDim.x;
    const int i0 = blockIdx.x * blockDim.x + threadIdx.x;
    for (int i = i0; i < BB * DC / 4; i += stride) {
        int base = i * 4;
        int m = base / DC, k = base % DC;
        f16x4 o;
        if (k < NIN) {
            float4 v = *(const float4*)(X + (size_t)m * SS * NIN + k);  // s = 0
            o[0] = (f16)v.x; o[1] = (f16)v.y; o[2] = (f16)v.z; o[3] = (f16)v.w;
        } else {
            o[0] = (f16)0.f; o[1] = (f16)0.f; o[2] = (f16)0.f; o[3] = (f16)0.f;
        }
        *(f16x4*)(comb + base) = o;
    }
    for (int i = i0; i < BB * DH / 4; i += stride)
        *(float4*)(h32 + i * 4) = make_float4(0.f, 0.f, 0.f, 0.f);
    for (int i = i0; i < 2 * 2048; i += stride) { ssum_ur[i] = 0.f; ssq_ur[i] = 0.f; }
    for (int i = i0; i < 2 * 1024; i += stride) { ssum_c[i] = 0.f; ssq_c[i] = 0.f; }
}

// ---------------- 64x64 GEMM job, 8 waves: 2x2 spatial (32x32) x 2-way K-split ----------------
// verified numerics (rounds 1-5).  C[64,64] = A[m0:64,K] * B[n0:64,K]^T
template<int KT, bool OEPI>
__device__ __forceinline__ void gemm_job(
    const f16* __restrict__ A, int lda, const f16* __restrict__ Bm,
    float* __restrict__ C, int ldc,
    float* __restrict__ ssum, float* __restrict__ ssq,
    const float* __restrict__ bo, float* __restrict__ outp, int so,
    int m0, int n0, f16 (*As)[64][72], f16 (*Bs)[64][72])
{
    constexpr int KH = KT / 2;
    constexpr int NC = KH / 64;
    const int tid  = threadIdx.x;
    const int lane = tid & 63;
    const int wave = tid >> 6;
    const int g    = tid >> 8;           // K-half group
    const int sq   = wave & 3, wm = sq >> 1, wn = sq & 1;
    const int t    = tid & 255;
    const int r0   = t >> 3, kg = t & 7;

    const f16* Ap  = A  + (size_t)(m0 + r0) * lda + g * KH + kg * 8;
    const f16* Ap2 = Ap + (size_t)32 * lda;
    const f16* Bp  = Bm + (size_t)(n0 + r0) * KT + g * KH + kg * 8;
    const f16* Bp2 = Bp + (size_t)32 * KT;

    f32x4 acc[2][2] = {};
    f16x8 pa0 = *(const f16x8*)Ap;
    f16x8 pa1 = *(const f16x8*)Ap2;
    f16x8 pb0 = *(const f16x8*)Bp;
    f16x8 pb1 = *(const f16x8*)Bp2;

    for (int c = 0; c < NC; ++c) {
        *(f16x8*)&As[g][r0][kg * 8]      = pa0;
        *(f16x8*)&As[g][r0 + 32][kg * 8] = pa1;
        *(f16x8*)&Bs[g][r0][kg * 8]      = pb0;
        *(f16x8*)&Bs[g][r0 + 32][kg * 8] = pb1;
        __syncthreads();
        if (c + 1 < NC) {
            pa0 = *(const f16x8*)(Ap  + (c + 1) * 64);
            pa1 = *(const f16x8*)(Ap2 + (c + 1) * 64);
            pb0 = *(const f16x8*)(Bp  + (c + 1) * 64);
            pb1 = *(const f16x8*)(Bp2 + (c + 1) * 64);
        }
#pragma unroll
        for (int ks = 0; ks < 2; ++ks) {
            const int kofs = ks * 32 + (lane >> 4) * 8;
            f16x8 a0 = *(const f16x8*)&As[g][wm * 32 + (lane & 15)][kofs];
            f16x8 a1 = *(const f16x8*)&As[g][wm * 32 + 16 + (lane & 15)][kofs];
            f16x8 b0 = *(const f16x8*)&Bs[g][wn * 32 + (lane & 15)][kofs];
            f16x8 b1 = *(const f16x8*)&Bs[g][wn * 32 + 16 + (lane & 15)][kofs];
            acc[0][0] = __builtin_amdgcn_mfma_f32_16x16x32_f16(a0, b0, acc[0][0], 0, 0, 0);
            acc[0][1] = __builtin_amdgcn_mfma_f32_16x16x32_f16(a0, b1, acc[0][1], 0, 0, 0);
            acc[1][0] = __builtin_amdgcn_mfma_f32_16x16x32_f16(a1, b0, acc[1][0], 0, 0, 0);
            acc[1][1] = __builtin_amdgcn_mfma_f32_16x16x32_f16(a1, b1, acc[1][1], 0, 0, 0);
        }
        __syncthreads();
    }

    // K-split reduction through LDS
    float* red = (float*)As;
    const int rbase = (sq * 64 + lane) * 20;
    if (g == 1) {
#pragma unroll
        for (int fm = 0; fm < 2; ++fm)
#pragma unroll
            for (int fn = 0; fn < 2; ++fn)
                *(f32x4*)&red[rbase + (fm * 2 + fn) * 4] = acc[fm][fn];
    }
    __syncthreads();
    if (g == 0) {
#pragma unroll
        for (int fm = 0; fm < 2; ++fm)
#pragma unroll
            for (int fn = 0; fn < 2; ++fn)
                acc[fm][fn] += *(const f32x4*)&red[rbase + (fm * 2 + fn) * 4];

#pragma unroll
        for (int fm = 0; fm < 2; ++fm) {
#pragma unroll
            for (int fn = 0; fn < 2; ++fn) {
                const int row = m0 + wm * 32 + fm * 16 + (lane >> 4) * 4;
                const int col = n0 + wn * 32 + fn * 16 + (lane & 15);
                if constexpr (OEPI) {
#pragma unroll
                    for (int i = 0; i < 4; ++i) {
                        float v = tanh_(acc[fm][fn][i] + bo[col]);
                        outp[(size_t)(row + i) * (SS * NOUT) + (size_t)so * NOUT + col] = v;
                    }
                } else {
#pragma unroll
                    for (int i = 0; i < 4; ++i)
                        C[(size_t)(row + i) * ldc + col] = acc[fm][fn][i];
                }
            }
        }
        if constexpr (!OEPI) {
#pragma unroll
            for (int fn = 0; fn < 2; ++fn) {
                float s1 = 0.f, s2 = 0.f;
#pragma unroll
                for (int fm = 0; fm < 2; ++fm)
#pragma unroll
                    for (int i = 0; i < 4; ++i) { float v = acc[fm][fn][i]; s1 += v; s2 += v * v; }
                s1 += __shfl_xor(s1, 16, 64); s1 += __shfl_xor(s1, 32, 64);
                s2 += __shfl_xor(s2, 16, 64); s2 += __shfl_xor(s2, 32, 64);
                if (lane < 16) {
                    const int col = n0 + wn * 32 + fn * 16 + lane;
                    atomicAdd(&ssum[col], s1);
                    atomicAdd(&ssq[col], s2);
                }
            }
        }
    }
}

// ---------------- c-GEMM job with FUSED reset-gate A-staging ----------------
// A[m][k] = comb_x for k<128, else sigmoid(sc*pre_r + bi) * h  computed on the fly.
__device__ __forceinline__ void gemm_job_cgate(
    const f16* __restrict__ comb, const float* __restrict__ pre_ur, const float* __restrict__ h32,
    const float* __restrict__ su, const float* __restrict__ qu,
    const float* __restrict__ g_r, const float* __restrict__ be_r,
    const f16* __restrict__ Bm,
    float* __restrict__ C, int ldc,
    float* __restrict__ ssum, float* __restrict__ ssq,
    int m0, int n0, f16 (*As)[64][72], f16 (*Bs)[64][72])
{
    constexpr int KT = DC, KH = KT / 2, NC = KH / 64;   // 1152, 576, 9
    const int tid  = threadIdx.x;
    const int lane = tid & 63;
    const int wave = tid >> 6;
    const int g    = tid >> 8;
    const int sq   = wave & 3, wm = sq >> 1, wn = sq & 1;
    const int t    = tid & 255;
    const int r0   = t >> 3, kg = t & 7;

    const f16* Bp  = Bm + (size_t)(n0 + r0) * KT + g * KH + kg * 8;
    const f16* Bp2 = Bp + (size_t)32 * KT;
    const int kb   = g * KH + kg * 8;

    f32x4 acc[2][2] = {};

    for (int c = 0; c < NC; ++c) {
        const int k8 = kb + c * 64;
        f16x8 a0, a1;
        if (k8 < NIN) {
            a0 = *(const f16x8*)(comb + (size_t)(m0 + r0) * DC + k8);
            a1 = *(const f16x8*)(comb + (size_t)(m0 + r0 + 32) * DC + k8);
        } else {
            const int j = k8 - NIN;
            // per-column affine: r = sigmoid(sc*p + bi)
            float sc[8], bi[8];
#pragma unroll
            for (int q = 0; q < 8; ++q) {
                float mu  = su[1024 + j + q] * (1.0f / 512.0f);
                float var = fmaxf(qu[1024 + j + q] * (1.0f / 512.0f) - mu * mu, 0.f);
                float a   = g_r[j + q] * rsqrtf(var + EPSV);
                sc[q] = a; bi[q] = be_r[j + q] - a * mu;
            }
            const float* pr0 = pre_ur + (size_t)(m0 + r0) * 2048 + 1024 + j;
            const float* pr1 = pre_ur + (size_t)(m0 + r0 + 32) * 2048 + 1024 + j;
            const float* hr0 = h32 + (size_t)(m0 + r0) * 1024 + j;
            const float* hr1 = h32 + (size_t)(m0 + r0 + 32) * 1024 + j;
            f32x4 p00 = *(const f32x4*)pr0, p01 = *(const f32x4*)(pr0 + 4);
            f32x4 p10 = *(const f32x4*)pr1, p11 = *(const f32x4*)(pr1 + 4);
            f32x4 h00 = *(const f32x4*)hr0, h01 = *(const f32x4*)(hr0 + 4);
            f32x4 h10 = *(const f32x4*)hr1, h11 = *(const f32x4*)(hr1 + 4);
#pragma unroll
            for (int q = 0; q < 4; ++q) {
                a0[q]     = (f16)(sigmoid_(sc[q] * p00[q] + bi[q]) * h00[q]);
                a0[q + 4] = (f16)(sigmoid_(sc[q + 4] * p01[q] + bi[q + 4]) * h01[q]);
                a1[q]     = (f16)(sigmoid_(sc[q] * p10[q] + bi[q]) * h10[q]);
                a1[q + 4] = (f16)(sigmoid_(sc[q + 4] * p11[q] + bi[q + 4]) * h11[q]);
            }
        }
        f16x8 b0v = *(const f16x8*)(Bp  + c * 64);
        f16x8 b1v = *(const f16x8*)(Bp2 + c * 64);
        *(f16x8*)&As[g][r0][kg * 8]      = a0;
        *(f16x8*)&As[g][r0 + 32][kg * 8] = a1;
        *(f16x8*)&Bs[g][r0][kg * 8]      = b0v;
        *(f16x8*)&Bs[g][r0 + 32][kg * 8] = b1v;
        __syncthreads();
#pragma unroll
        for (int ks = 0; ks < 2; ++ks) {
            const int kofs = ks * 32 + (lane >> 4) * 8;
            f16x8 fa0 = *(const f16x8*)&As[g][wm * 32 + (lane & 15)][kofs];
            f16x8 fa1 = *(const f16x8*)&As[g][wm * 32 + 16 + (lane & 15)][kofs];
            f16x8 fb0 = *(const f16x8*)&Bs[g][wn * 32 + (lane & 15)][kofs];
            f16x8 fb1 = *(const f16x8*)&Bs[g][wn * 32 + 16 + (lane & 15)][kofs];
            acc[0][0] = __builtin_amdgcn_mfma_f32_16x16x32_f16(fa0, fb0, acc[0][0], 0, 0, 0);
            acc[0][1] = __builtin_amdgcn_mfma_f32_16x16x32_f16(fa0, fb1, acc[0][1], 0, 0, 0);
            acc[1][0] = __builtin_amdgcn_mfma_f32_16x16x32_f16(fa1, fb0, acc[1][0], 0, 0, 0);
            acc[1][1] = __builtin_amdgcn_mfma_f32_16x16x32_f16(fa1, fb1, acc[1][1], 0, 0, 0);
        }
        __syncthreads();
    }

    float* red = (float*)As;
    const int rbase = (sq * 64 + lane) * 20;
    if (g == 1) {
#pragma unroll
        for (int fm = 0; fm < 2; ++fm)
#pragma unroll
            for (int fn = 0; fn < 2; ++fn)
                *(f32x4*)&red[rbase + (fm * 2 + fn) * 4] = acc[fm][fn];
    }
    __syncthreads();
    if (g == 0) {
#pragma unroll
        for (int fm = 0; fm < 2; ++fm)
#pragma unroll
            for (int fn = 0; fn < 2; ++fn)
                acc[fm][fn] += *(const f32x4*)&red[rbase + (fm * 2 + fn) * 4];

#pragma unroll
        for (int fm = 0; fm < 2; ++fm)
#pragma unroll
            for (int fn = 0; fn < 2; ++fn) {
                const int row = m0 + wm * 32 + fm * 16 + (lane >> 4) * 4;
                const int col = n0 + wn * 32 + fn * 16 + (lane & 15);
#pragma unroll
                for (int i = 0; i < 4; ++i)
                    C[(size_t)(row + i) * ldc + col] = acc[fm][fn][i];
            }
#pragma unroll
        for (int fn = 0; fn < 2; ++fn) {
            float s1 = 0.f, s2 = 0.f;
#pragma unroll
            for (int fm = 0; fm < 2; ++fm)
#pragma unroll
                for (int i = 0; i < 4; ++i) { float v = acc[fm][fn][i]; s1 += v; s2 += v * v; }
            s1 += __shfl_xor(s1, 16, 64); s1 += __shfl_xor(s1, 32, 64);
            s2 += __shfl_xor(s2, 16, 64); s2 += __shfl_xor(s2, 32, 64);
            if (lane < 16) {
                const int col = n0 + wn * 32 + fn * 16 + lane;
                atomicAdd(&ssum[col], s1);
                atomicAdd(&ssq[col], s2);
            }
        }
    }
}

// ---------------- phase 1: ur-GEMM, clean 256-block grid (1 block/CU) ----------------
__global__ __launch_bounds__(512, 2)
void k_ur(const f16* __restrict__ comb, const f16* __restrict__ Wur,
          float* __restrict__ pre_ur, float* __restrict__ ssum, float* __restrict__ ssq)
{
    __shared__ __align__(16) f16 smem[2][2][64][72];
    const int b = blockIdx.x;
    const int m0 = (b >> 5) * 64, n0 = (b & 31) * 64;
    gemm_job<DC, false>(comb, DC, Wur, pre_ur, 2048, ssum, ssq,
                        nullptr, nullptr, 0, m0, n0, smem[0], smem[1]);
}

// ---------------- phase 2: c-GEMM+fused gate (128 jobs) + o(s-1) (16 jobs) ----------------
__global__ __launch_bounds__(512, 2)
void k_cgo(const f16* __restrict__ comb, const float* __restrict__ pre_ur, const float* __restrict__ h32,
           const f16* __restrict__ Wh16, const f16* __restrict__ Wo16,
           float* __restrict__ pre_c,
           const float* __restrict__ su, const float* __restrict__ qu,
           float* __restrict__ sc_, float* __restrict__ qc_,
           const float* __restrict__ g_r, const float* __restrict__ be_r,
           const float* __restrict__ b_o, float* __restrict__ outp, int s)
{
    __shared__ __align__(16) f16 smem[2][2][64][72];
    const int b = blockIdx.x;
    if (b < 128) {
        const int m0 = (b >> 4) * 64, n0 = (b & 15) * 64;
        gemm_job_cgate(comb, pre_ur, h32, su, qu, g_r, be_r, Wh16,
                       pre_c, 1024, sc_, qc_, m0, n0, smem[0], smem[1]);
    } else {
        if (s == 0) return;
        const int j = b - 128;
        const int m0 = (j >> 1) * 64, n0 = (j & 1) * 64;
        gemm_job<DH, true>(comb + NIN, DC, Wo16, nullptr, 0, nullptr, nullptr,
                           b_o, outp, s - 1, m0, n0, smem[0], smem[1]);
    }
}

// ---------------- final o for s = 255 ----------------
__global__ __launch_bounds__(512, 2)
void k_o16(const f16* __restrict__ comb, const f16* __restrict__ Wo16,
           const float* __restrict__ b_o, float* __restrict__ outp)
{
    __shared__ __align__(16) f16 smem[2][2][64][72];
    const int b = blockIdx.x;
    const int m0 = (b >> 1) * 64, n0 = (b & 1) * 64;
    gemm_job<DH, true>(comb + NIN, DC, Wo16, nullptr, 0, nullptr, nullptr,
                       b_o, outp, SS - 1, m0, n0, smem[0], smem[1]);
}

// ---------------- phase 3: u, c, h_new; prep next step ----------------
__global__ __launch_bounds__(256)
void k_upd(const float* __restrict__ pre_ur, const float* __restrict__ pre_c,
           float* __restrict__ h32, f16* __restrict__ comb,
           const float* __restrict__ ssum_ur, const float* __restrict__ ssq_ur,
           const float* __restrict__ ssum_c, const float* __restrict__ ssq_c,
           float* __restrict__ zsum_ur, float* __restrict__ zsq_ur,
           float* __restrict__ zsum_c, float* __restrict__ zsq_c,
           const float* __restrict__ X,
           const float* __restrict__ g_u, const float* __restrict__ be_u,
           const float* __restrict__ g_h, const float* __restrict__ be_h,
           int s)
{
    const int idx = blockIdx.x * 256 + threadIdx.x;
    const int m = idx >> 8, j4 = (idx & 255) << 2;
    float4 puv = *(const float4*)(pre_ur + (size_t)m * 2048 + j4);
    float4 pcv = *(const float4*)(pre_c + (size_t)m * 1024 + j4);
    float4 hv  = *(const float4*)(h32 + (size_t)m * 1024 + j4);
    float pu[4] = {puv.x, puv.y, puv.z, puv.w};
    float pc[4] = {pcv.x, pcv.y, pcv.z, pcv.w};
    float h[4]  = {hv.x, hv.y, hv.z, hv.w};
    float hn[4];
    f16x4 o;
#pragma unroll
    for (int t = 0; t < 4; ++t) {
        const int col = j4 + t;
        float mu_u  = ssum_ur[col] * (1.0f / 512.0f);
        float var_u = fmaxf(ssq_ur[col] * (1.0f / 512.0f) - mu_u * mu_u, 0.f);
        float u = sigmoid_(g_u[col] * ((pu[t] - mu_u) * rsqrtf(var_u + EPSV)) + be_u[col]);
        float mu_c  = ssum_c[col] * (1.0f / 512.0f);
        float var_c = fmaxf(ssq_c[col] * (1.0f / 512.0f) - mu_c * mu_c, 0.f);
        float c = tanh_(g_h[col] * ((pc[t] - mu_c) * rsqrtf(var_c + EPSV)) + be_h[col]);
        float hnew = (1.f - u) * c + u * h[t];
        hn[t] = hnew; o[t] = (f16)hnew;
    }
    *(float4*)(h32 + (size_t)m * 1024 + j4) = make_float4(hn[0], hn[1], hn[2], hn[3]);
    *(f16x4*)(comb + (size_t)m * DC + NIN + j4) = o;
    if (j4 < NIN && s + 1 < SS) {
        float4 xv = *(const float4*)(X + (size_t)m * SS * NIN + (size_t)(s + 1) * NIN + j4);
        f16x4 xo; xo[0] = (f16)xv.x; xo[1] = (f16)xv.y; xo[2] = (f16)xv.z; xo[3] = (f16)xv.w;
        *(f16x4*)(comb + (size_t)m * DC + j4) = xo;
    }
    if (idx < 2048) { zsum_ur[idx] = 0.f; zsq_ur[idx] = 0.f; }
    if (idx < 1024) { zsum_c[idx] = 0.f; zsq_c[idx] = 0.f; }
}

// ---------------- host launch ----------------
extern "C" void kernel_launch(void* const* d_in, const int* in_sizes, int n_in,
                              void* d_out, int out_size, void* d_ws, size_t ws_size,
                              hipStream_t stream)
{
    const float* X    = (const float*)d_in[0];
    const float* W_u  = (const float*)d_in[1];
    const float* W_r  = (const float*)d_in[3];
    const float* W_h  = (const float*)d_in[5];
    const float* W_o  = (const float*)d_in[7];
    const float* b_o  = (const float*)d_in[8];
    const float* g_u  = (const float*)d_in[9];
    const float* be_u = (const float*)d_in[10];
    const float* g_r  = (const float*)d_in[11];
    const float* be_r = (const float*)d_in[12];
    const float* g_h  = (const float*)d_in[13];
    const float* be_h = (const float*)d_in[14];
    float* out = (float*)d_out;

    char* p = (char*)d_ws;
    auto alloc = [&](size_t bytes) { char* r = p; p += (bytes + 255) & ~(size_t)255; return r; };
    f16*   comb    = (f16*)alloc((size_t)BB * DC * 2);
    f16*   Wur     = (f16*)alloc((size_t)2048 * DC * 2);
    f16*   Wh16    = (f16*)alloc((size_t)DH * DC * 2);
    f16*   Wo16    = (f16*)alloc((size_t)NOUT * DH * 2);
    float* pre_ur  = (float*)alloc((size_t)BB * 2048 * 4);
    float* pre_c   = (float*)alloc((size_t)BB * DH * 4);
    float* h32     = (float*)alloc((size_t)BB * DH * 4);
    float* ssum_ur = (float*)alloc(2 * 2048 * 4);
    float* ssq_ur  = (float*)alloc(2 * 2048 * 4);
    float* ssum_c  = (float*)alloc(2 * 1024 * 4);
    float* ssq_c   = (float*)alloc(2 * 1024 * 4);

    k_convert<<<1024, 256, 0, stream>>>(W_u, W_r, W_h, W_o, Wur, Wh16, Wo16);
    k_init<<<1024, 256, 0, stream>>>(X, comb, h32, ssum_ur, ssq_ur, ssum_c, ssq_c);

    for (int s = 0; s < SS; ++s) {
        const int par = s & 1, nxt = 1 - par;
        // phase 1: pre_ur = comb @ Wur^T (+stats)
        k_ur<<<256, 512, 0, stream>>>(comb, Wur, pre_ur,
                                      ssum_ur + par * 2048, ssq_ur + par * 2048);
        // phase 2: pre_c = [x, r*h] @ Wh^T (+stats, gate fused)  ||  o(s-1)
        k_cgo<<<144, 512, 0, stream>>>(comb, pre_ur, h32, Wh16, Wo16, pre_c,
                                       ssum_ur + par * 2048, ssq_ur + par * 2048,
                                       ssum_c + par * 1024, ssq_c + par * 1024,
                                       g_r, be_r, b_o, out, s);
        // phase 3: u, c, h_new; prep next step; zero next-parity stats
        k_upd<<<512, 256, 0, stream>>>(pre_ur, pre_c, h32, comb,
            ssum_ur + par * 2048, ssq_ur + par * 2048,
            ssum_c + par * 1024, ssq_c + par * 1024,
            ssum_ur + nxt * 2048, ssq_ur + nxt * 2048,
            ssum_c + nxt * 1024, ssq_c + nxt * 1024,
            X, g_u, be_u, g_h, be_h, s);
    }
    // final o for s = 255 (comb h-region holds h_new(255))
    k_o16<<<16, 512, 0, stream>>>(comb, Wo16, b_o, out);
}